// Round 1
// baseline (108.165 us; speedup 1.0000x reference)
//
#include <hip/hip_runtime.h>

#define K_RBF   32
#define LUT_N   256           // points over [LUT_LO, LUT_HI]; intervals 0..254
#define LUT_LO  (-8.0f)
#define LUT_HI  (8.0f)
// h = 16/256 = 0.0625, inv_h = 16
#define LUT_INVH 16.0f

// Reference constants at float32 precision, exactly as jnp.float32(...)
#define DT_F      0.005f
#define M_INV_F   ((float)(1.0 / 95.452))
#define OFFST_F   (-3.2902f)
#define F_V_F     214.9261f
#define F_C_F     19.3607f

#if __has_builtin(__builtin_amdgcn_exp2f)
#define EXP2(x) __builtin_amdgcn_exp2f(x)
#else
#define EXP2(x) exp2f(x)
#endif

// Native clang vectors — accepted by __builtin_nontemporal_{load,store}.
typedef float vfloat4 __attribute__((ext_vector_type(4)));
typedef float vfloat2 __attribute__((ext_vector_type(2)));

// ---------------------------------------------------------------------------
// Single fused kernel, v2 (polish pass).
// Phase 1 (per block, hidden under streaming): build a 256-entry LUT of
//   {f(x_i), f(x_{i+1})-f(x_i)} as float2 in LDS. One ds_read_b64 per
//   element in the hot loop (v1 did two dependent b32 reads: F[idx],
//   F[idx+1]). Setup cost: 64 exp2/thread, ~0.3 us, amortized.
// Phase 2: grid-stride streaming, 4 elements/thread-iter; every global
//   access is 16 B/lane (2x float4 states, 1x float4 u, 2x float4 out),
//   nontemporal. RK4 tail collapsed as in v1:
//     st1 = C6*k1*(6 - M_INV*(4h+DT)*(FVC+f'))
//     st0 = DT*x + C6*(4h+DT)*k1
//   (identical math; y0 dead; yd==k1, k3==k2. LUT interp error ~2e-2 in
//   f-space attenuates by ~3.5e-5 into the output -> ~1e-6, far under the
//   1.33e-3 threshold.)
// ---------------------------------------------------------------------------
__launch_bounds__(256)
__global__ void rk4_rbf_kernel(const vfloat4* __restrict__ u4,
                               const vfloat4* __restrict__ states4,
                               const float*  __restrict__ centers,
                               const float*  __restrict__ log_sigmas,
                               const float*  __restrict__ wts,
                               const float*  __restrict__ bptr,
                               vfloat4* __restrict__ out4,
                               int n_quads) {
    __shared__ float4  P[K_RBF];     // {A, B, E, w} per RBF
    __shared__ vfloat2 F2[LUT_N];    // {f(x_i), f(x_{i+1})-f(x_i)}, 2 KB

    if (threadIdx.x < K_RBF) {
        const float LOG2E = 1.4426950408889634f;
        int k = threadIdx.x;
        float s  = __expf(log_sigmas[k]);
        float s2 = s * s;
        float c  = centers[k];
        P[k] = make_float4(-s2 * LOG2E,                 // A
                           2.0f * s2 * c * LOG2E,       // B
                           -s2 * c * c * LOG2E,         // E
                           wts[k]);                     // w
    }
    __syncthreads();

    {   // one LUT interval per thread (blockDim.x == LUT_N == 256)
        const float H = (LUT_HI - LUT_LO) / (float)LUT_N;
        float xg0 = LUT_LO + (float)threadIdx.x * H;
        float xg1 = LUT_LO + (float)(threadIdx.x + 1) * H;
        float bv  = bptr[0];
        float f0 = bv, f1 = bv;
#pragma unroll
        for (int k = 0; k < K_RBF; ++k) {
            float4 p = P[k];
            float q0 = fmaf(fmaf(p.x, xg0, p.y), xg0, p.z);
            float q1 = fmaf(fmaf(p.x, xg1, p.y), xg1, p.z);
            f0 = fmaf(p.w, EXP2(q0), f0);
            f1 = fmaf(p.w, EXP2(q1), f1);
        }
        vfloat2 e = { f0, f1 - f0 };
        F2[threadIdx.x] = e;
    }
    __syncthreads();

    const float FVC = F_V_F + F_C_F;
    const float C6  = DT_F / 6.0f;
    const float C1  = 0.015f * M_INV_F;   // M_INV*(4h+DT)
    const float C2  = C6 * 0.015f;        // C6*(4h+DT)

    int stride = gridDim.x * blockDim.x;
    for (int i = blockIdx.x * blockDim.x + threadIdx.x; i < n_quads; i += stride) {
        vfloat4 sA = __builtin_nontemporal_load(&states4[2 * i]);     // y0a,y1a,y0b,y1b
        vfloat4 sB = __builtin_nontemporal_load(&states4[2 * i + 1]); // y0c,y1c,y0d,y1d
        vfloat4 uu = __builtin_nontemporal_load(&u4[i]);

        float x[4]  = { sA.y, sA.w, sB.y, sB.w };   // y1 (y0 is dead)
        float uv[4] = { uu.x, uu.y, uu.z, uu.w };
        float o[8];
#pragma unroll
        for (int e = 0; e < 4; ++e) {
            float t   = (x[e] - LUT_LO) * LUT_INVH;
            t = fminf(fmaxf(t, 0.0f), (float)(LUT_N - 2) + 0.999f);
            int   idx = (int)t;
            float fr  = t - (float)idx;
            vfloat2 fe = F2[idx];                   // one ds_read_b64
            float f   = fmaf(fr, fe.y, fe.x);       // f(x) incl. b
            float fp  = fe.y * LUT_INVH;            // f'(x)

            float k1 = (uv[e] - FVC * x[e] - (OFFST_F + f)) * M_INV_F;
            float g  = 6.0f - C1 * (FVC + fp);
            o[2 * e]     = fmaf(C2, k1, DT_F * x[e]);   // st0
            o[2 * e + 1] = C6 * k1 * g;                 // st1
        }

        vfloat4 ovA = { o[0], o[1], o[2], o[3] };
        vfloat4 ovB = { o[4], o[5], o[6], o[7] };
        __builtin_nontemporal_store(ovA, &out4[2 * i]);
        __builtin_nontemporal_store(ovB, &out4[2 * i + 1]);
    }
}

extern "C" void kernel_launch(void* const* d_in, const int* in_sizes, int n_in,
                              void* d_out, int out_size, void* d_ws, size_t ws_size,
                              hipStream_t stream) {
    const float* u        = (const float*)d_in[0];   // (B,)
    const float* states   = (const float*)d_in[1];   // (B,2)
    const float* centers  = (const float*)d_in[2];   // (32,)
    const float* logsig   = (const float*)d_in[3];   // (32,)
    const float* w        = (const float*)d_in[4];   // (32,)
    const float* b        = (const float*)d_in[5];   // (1,)

    int B = in_sizes[0];
    int n_quads = B / 4;                             // 1,048,576
    int block = 256;                                 // == LUT_N
    int grid  = 2048;                                // grid-stride: 2 quads/thread
    rk4_rbf_kernel<<<grid, block, 0, stream>>>(
        (const vfloat4*)u, (const vfloat4*)states,
        centers, logsig, w, b, (vfloat4*)d_out, n_quads);
}